// Round 1
// baseline (183.770 us; speedup 1.0000x reference)
//
#include <hip/hip_runtime.h>
#include <hip/hip_bf16.h>

#define B_  8
#define S_  2048
#define DIN 1024
#define DH  64

typedef __bf16 bf16;
typedef __attribute__((ext_vector_type(8))) __bf16 bf16x8;
typedef __attribute__((ext_vector_type(4))) float f32x4;

// ---------------- weight f32 -> bf16 ----------------
__global__ __launch_bounds__(256) void wconv_kernel(const float* __restrict__ wq,
                                                    const float* __restrict__ wk,
                                                    const float* __restrict__ wv,
                                                    bf16* __restrict__ wb) {
  int i = blockIdx.x * 256 + threadIdx.x;   // grid covers DH*DIN exactly
  const int N = DH * DIN;
  wb[i]       = (bf16)wq[i];
  wb[N + i]   = (bf16)wk[i];
  wb[2*N + i] = (bf16)wv[i];
}

// ---------------- fused QKV projection ----------------
// grid: (M/64, 3). Each block: 64 rows x 64 cols. Wave w: rows w*16..w*16+16.
__global__ __launch_bounds__(256) void proj_kernel(
    const float* __restrict__ inq, const float* __restrict__ ink, const float* __restrict__ inv,
    const bf16* __restrict__ wb_all,
    bf16* __restrict__ qb, bf16* __restrict__ kb, bf16* __restrict__ vt) {
  const int p = blockIdx.y;
  const float* in = (p == 0) ? inq : ((p == 1) ? ink : inv);
  const bf16* wb = wb_all + (size_t)p * DH * DIN;
  const int lane = threadIdx.x & 63;
  const int wv   = threadIdx.x >> 6;
  const int col16 = lane & 15, g = lane >> 4;
  const int r = blockIdx.x * 64 + wv * 16 + col16;   // A-frag row (row = lane%16)

  f32x4 acc[4] = {};
  const float* arow = in + (size_t)r * DIN + g * 8;
  #pragma unroll 4
  for (int k0 = 0; k0 < DIN; k0 += 32) {
    const float4* ap = reinterpret_cast<const float4*>(arow + k0);
    float4 a0 = ap[0], a1 = ap[1];
    bf16x8 av;
    av[0]=(bf16)a0.x; av[1]=(bf16)a0.y; av[2]=(bf16)a0.z; av[3]=(bf16)a0.w;
    av[4]=(bf16)a1.x; av[5]=(bf16)a1.y; av[6]=(bf16)a1.z; av[7]=(bf16)a1.w;
    #pragma unroll
    for (int n = 0; n < 4; n++) {
      bf16x8 bv = *reinterpret_cast<const bf16x8*>(wb + (size_t)(n*16 + col16) * DIN + k0 + g * 8);
      acc[n] = __builtin_amdgcn_mfma_f32_16x16x32_bf16(av, bv, acc[n], 0, 0, 0);
    }
  }
  // C layout: col = lane&15, row = (lane>>4)*4 + reg
  const int rowbase = blockIdx.x * 64 + wv * 16 + g * 4;
  if (p < 2) {
    bf16* out = (p == 0) ? qb : kb;
    #pragma unroll
    for (int n = 0; n < 4; n++)
      #pragma unroll
      for (int rg = 0; rg < 4; rg++)
        out[(size_t)(rowbase + rg) * DH + n*16 + col16] = (bf16)acc[n][rg];
  } else {
    // V stored transposed: vt[b][d][s]
    #pragma unroll
    for (int n = 0; n < 4; n++)
      #pragma unroll
      for (int rg = 0; rg < 4; rg++) {
        int rr = rowbase + rg;
        int bb = rr >> 11, s = rr & 2047;
        vt[((size_t)bb * DH + n*16 + col16) * S_ + s] = (bf16)acc[n][rg];
      }
  }
}

// ---------------- causal flash attention ----------------
// grid: (S/64, B). Block: 4 waves, wave w owns q rows qt*64 + w*16 .. +16.
__global__ __launch_bounds__(256) void attn_kernel(
    const bf16* __restrict__ qb, const bf16* __restrict__ kb, const bf16* __restrict__ vt,
    float* __restrict__ out) {
  const int qt = blockIdx.x;
  const int b  = blockIdx.y;
  const int lane = threadIdx.x & 63;
  const int wv   = threadIdx.x >> 6;
  const int col16 = lane & 15, g = lane >> 4;
  const int row0 = qt * 64 + wv * 16;   // in-batch q row base for this wave

  __shared__ bf16 plds[4][16 * 64];
  bf16* pl = plds[wv];

  // Q fragments (held for whole kernel): a[i] = Q[row=lane%16][k=(lane/16)*8+i]
  bf16x8 qf[2];
  {
    const bf16* qrow = qb + ((size_t)(b * S_ + row0 + col16)) * DH + g * 8;
    qf[0] = *reinterpret_cast<const bf16x8*>(qrow);
    qf[1] = *reinterpret_cast<const bf16x8*>(qrow + 32);
  }

  f32x4 acc[4] = {};
  float m_r[4], l_r[4];
  #pragma unroll
  for (int i = 0; i < 4; i++) { m_r[i] = -1e30f; l_r[i] = 0.f; }

  for (int t = 0; t <= qt; ++t) {
    const int kvb = t * 64;
    // ---- S = Q K^T ----
    f32x4 s[4] = {};
    #pragma unroll
    for (int n = 0; n < 4; n++) {
      const bf16* krow = kb + ((size_t)(b * S_ + kvb + n*16 + col16)) * DH + g * 8;
      bf16x8 kf0 = *reinterpret_cast<const bf16x8*>(krow);
      bf16x8 kf1 = *reinterpret_cast<const bf16x8*>(krow + 32);
      s[n] = __builtin_amdgcn_mfma_f32_16x16x32_bf16(qf[0], kf0, s[n], 0, 0, 0);
      s[n] = __builtin_amdgcn_mfma_f32_16x16x32_bf16(qf[1], kf1, s[n], 0, 0, 0);
    }
    // ---- scale + causal mask ----
    float vals[4][4];
    const bool diag = (t == qt);
    #pragma unroll
    for (int n = 0; n < 4; n++)
      #pragma unroll
      for (int rg = 0; rg < 4; rg++) {
        float v = s[n][rg] * 0.125f;
        if (diag) {
          int kvp = kvb + n*16 + col16;
          int qp  = row0 + g*4 + rg;
          if (kvp > qp) v = -1e30f;
        }
        vals[n][rg] = v;
      }
    // ---- row max (reduce across the 16 lanes holding this row) ----
    float rmax[4];
    #pragma unroll
    for (int rg = 0; rg < 4; rg++)
      rmax[rg] = fmaxf(fmaxf(vals[0][rg], vals[1][rg]), fmaxf(vals[2][rg], vals[3][rg]));
    #pragma unroll
    for (int off = 1; off < 16; off <<= 1)
      #pragma unroll
      for (int rg = 0; rg < 4; rg++)
        rmax[rg] = fmaxf(rmax[rg], __shfl_xor(rmax[rg], off));
    // ---- online softmax update ----
    float scl[4], rsum[4];
    #pragma unroll
    for (int rg = 0; rg < 4; rg++) {
      float mn = fmaxf(m_r[rg], rmax[rg]);
      scl[rg] = __expf(m_r[rg] - mn);
      m_r[rg] = mn;
      rsum[rg] = 0.f;
    }
    #pragma unroll
    for (int n = 0; n < 4; n++)
      #pragma unroll
      for (int rg = 0; rg < 4; rg++) {
        float p = __expf(vals[n][rg] - m_r[rg]);
        vals[n][rg] = p;
        rsum[rg] += p;
      }
    #pragma unroll
    for (int off = 1; off < 16; off <<= 1)
      #pragma unroll
      for (int rg = 0; rg < 4; rg++)
        rsum[rg] += __shfl_xor(rsum[rg], off);
    #pragma unroll
    for (int rg = 0; rg < 4; rg++)
      l_r[rg] = l_r[rg] * scl[rg] + rsum[rg];
    #pragma unroll
    for (int n = 0; n < 4; n++)
      #pragma unroll
      for (int rg = 0; rg < 4; rg++)
        acc[n][rg] *= scl[rg];
    // ---- P -> LDS (XOR-swizzled), C-layout write ----
    #pragma unroll
    for (int n = 0; n < 4; n++)
      #pragma unroll
      for (int rg = 0; rg < 4; rg++) {
        int row = g*4 + rg;
        int idx = (row * 64 + n*16 + col16) ^ ((row & 7) << 3);
        pl[idx] = (bf16)vals[n][rg];
      }
    // ---- read P back as A-fragments (same swizzle) ----
    bf16x8 pa[2];
    {
      int row = col16;
      int i0 = (row * 64 + 0  + g * 8) ^ ((row & 7) << 3);
      int i1 = (row * 64 + 32 + g * 8) ^ ((row & 7) << 3);
      pa[0] = *reinterpret_cast<const bf16x8*>(&pl[i0]);
      pa[1] = *reinterpret_cast<const bf16x8*>(&pl[i1]);
    }
    // ---- O += P V  (V^T layout gives contiguous k per lane) ----
    #pragma unroll
    for (int nd = 0; nd < 4; nd++) {
      const bf16* vrow = vt + ((size_t)(b * DH + nd*16 + col16)) * S_ + kvb + g * 8;
      bf16x8 v0 = *reinterpret_cast<const bf16x8*>(vrow);
      bf16x8 v1 = *reinterpret_cast<const bf16x8*>(vrow + 32);
      acc[nd] = __builtin_amdgcn_mfma_f32_16x16x32_bf16(pa[0], v0, acc[nd], 0, 0, 0);
      acc[nd] = __builtin_amdgcn_mfma_f32_16x16x32_bf16(pa[1], v1, acc[nd], 0, 0, 0);
    }
  }
  // ---- normalize + store f32 ----
  #pragma unroll
  for (int n = 0; n < 4; n++)
    #pragma unroll
    for (int rg = 0; rg < 4; rg++) {
      int rr = row0 + g*4 + rg;
      out[((size_t)b * S_ + rr) * DH + n*16 + col16] = acc[n][rg] / l_r[rg];
    }
}

extern "C" void kernel_launch(void* const* d_in, const int* in_sizes, int n_in,
                              void* d_out, int out_size, void* d_ws, size_t ws_size,
                              hipStream_t stream) {
  const float* q  = (const float*)d_in[0];
  const float* k  = (const float*)d_in[1];
  const float* v  = (const float*)d_in[2];
  const float* wq = (const float*)d_in[3];
  const float* wk = (const float*)d_in[4];
  const float* wv = (const float*)d_in[5];

  char* ws = (char*)d_ws;
  bf16* Wb = (bf16*)(ws);                               // 3*64*1024*2 = 384 KB
  bf16* Qb = (bf16*)(ws + (512 << 10));                 // 2 MB
  bf16* Kb = (bf16*)(ws + (512 << 10) + (2 << 20));     // 2 MB
  bf16* Vt = (bf16*)(ws + (512 << 10) + (4 << 20));     // 2 MB (transposed [B][DH][S])

  wconv_kernel<<<dim3(DH * DIN / 256), 256, 0, stream>>>(wq, wk, wv, Wb);
  proj_kernel<<<dim3(B_ * S_ / 64, 3), 256, 0, stream>>>(q, k, v, Wb, Qb, Kb, Vt);
  attn_kernel<<<dim3(S_ / 64, B_), 256, 0, stream>>>(Qb, Kb, Vt, (float*)d_out);
}

// Round 2
// 127.088 us; speedup vs baseline: 1.4460x; 1.4460x over previous
//
#include <hip/hip_runtime.h>
#include <hip/hip_bf16.h>

#define B_  8
#define S_  2048
#define DIN 1024
#define DH  64

typedef __bf16 bf16;
typedef __attribute__((ext_vector_type(8))) __bf16 bf16x8;
typedef __attribute__((ext_vector_type(4))) float f32x4;

// ---------------- weight f32 -> bf16 ----------------
__global__ __launch_bounds__(256) void wconv_kernel(const float* __restrict__ wq,
                                                    const float* __restrict__ wk,
                                                    const float* __restrict__ wv,
                                                    bf16* __restrict__ wb) {
  int i = blockIdx.x * 256 + threadIdx.x;
  const int N = DH * DIN;
  wb[i]       = (bf16)wq[i];
  wb[N + i]   = (bf16)wk[i];
  wb[2*N + i] = (bf16)wv[i];
}

// ---------------- fused QKV projection ----------------
__global__ __launch_bounds__(256) void proj_kernel(
    const float* __restrict__ inq, const float* __restrict__ ink, const float* __restrict__ inv,
    const bf16* __restrict__ wb_all,
    bf16* __restrict__ qb, bf16* __restrict__ kb, bf16* __restrict__ vt) {
  const int p = blockIdx.y;
  const float* in = (p == 0) ? inq : ((p == 1) ? ink : inv);
  const bf16* wb = wb_all + (size_t)p * DH * DIN;
  const int lane = threadIdx.x & 63;
  const int wv   = threadIdx.x >> 6;
  const int col16 = lane & 15, g = lane >> 4;
  const int r = blockIdx.x * 64 + wv * 16 + col16;

  f32x4 acc[4] = {};
  const float* arow = in + (size_t)r * DIN + g * 8;
  #pragma unroll 4
  for (int k0 = 0; k0 < DIN; k0 += 32) {
    const float4* ap = reinterpret_cast<const float4*>(arow + k0);
    float4 a0 = ap[0], a1 = ap[1];
    bf16x8 av;
    av[0]=(bf16)a0.x; av[1]=(bf16)a0.y; av[2]=(bf16)a0.z; av[3]=(bf16)a0.w;
    av[4]=(bf16)a1.x; av[5]=(bf16)a1.y; av[6]=(bf16)a1.z; av[7]=(bf16)a1.w;
    #pragma unroll
    for (int n = 0; n < 4; n++) {
      bf16x8 bv = *reinterpret_cast<const bf16x8*>(wb + (size_t)(n*16 + col16) * DIN + k0 + g * 8);
      acc[n] = __builtin_amdgcn_mfma_f32_16x16x32_bf16(av, bv, acc[n], 0, 0, 0);
    }
  }
  const int rowbase = blockIdx.x * 64 + wv * 16 + g * 4;
  if (p < 2) {
    bf16* out = (p == 0) ? qb : kb;
    #pragma unroll
    for (int n = 0; n < 4; n++)
      #pragma unroll
      for (int rg = 0; rg < 4; rg++)
        out[(size_t)(rowbase + rg) * DH + n*16 + col16] = (bf16)acc[n][rg];
  } else {
    #pragma unroll
    for (int n = 0; n < 4; n++)
      #pragma unroll
      for (int rg = 0; rg < 4; rg++) {
        int rr = rowbase + rg;
        int bb = rr >> 11, s = rr & 2047;
        vt[((size_t)bb * DH + n*16 + col16) * S_ + s] = (bf16)acc[n][rg];
      }
  }
}

// ---------------- causal flash attention, KV-split across 8 waves ----------------
// grid: (S/16, B), block = 512 threads (8 waves).
// Block owns q rows qt*16..qt*16+15. Wave w processes kv tiles t = w, w+8, ...
// then block-combines the 8 partial (m,l,acc) via LDS.
__global__ __launch_bounds__(512) void attn_kernel(
    const bf16* __restrict__ qb, const bf16* __restrict__ kb, const bf16* __restrict__ vt,
    float* __restrict__ out) {
  const int qt = blockIdx.x;
  const int b  = blockIdx.y;
  const int lane = threadIdx.x & 63;
  const int w    = threadIdx.x >> 6;       // wave 0..7
  const int col16 = lane & 15, g = lane >> 4;
  const int row0 = qt * 16;                // q rows row0..row0+15

  __shared__ float pacc[8][16][64];
  __shared__ float pm[8][16];
  __shared__ float pl_[8][16];
  __shared__ bf16 plds[8][16 * 64];
  bf16* pl = plds[w];

  // Q fragments: a[i] = Q[row=lane%16][k=(lane/16)*8+i]
  bf16x8 qf[2];
  {
    const bf16* qrow = qb + ((size_t)(b * S_ + row0 + col16)) * DH + g * 8;
    qf[0] = *reinterpret_cast<const bf16x8*>(qrow);
    qf[1] = *reinterpret_cast<const bf16x8*>(qrow + 32);
  }

  f32x4 acc[4] = {};
  float m_r[4], l_r[4];
  #pragma unroll
  for (int i = 0; i < 4; i++) { m_r[i] = -1e30f; l_r[i] = 0.f; }

  const int nt = (qt + 4) >> 2;            // causal kv-tile count (KVBLK=64)

  for (int t = w; t < nt; t += 8) {
    const int kvb = t * 64;
    // ---- S = Q K^T ----
    f32x4 s[4] = {};
    #pragma unroll
    for (int n = 0; n < 4; n++) {
      const bf16* krow = kb + ((size_t)(b * S_ + kvb + n*16 + col16)) * DH + g * 8;
      bf16x8 kf0 = *reinterpret_cast<const bf16x8*>(krow);
      bf16x8 kf1 = *reinterpret_cast<const bf16x8*>(krow + 32);
      s[n] = __builtin_amdgcn_mfma_f32_16x16x32_bf16(qf[0], kf0, s[n], 0, 0, 0);
      s[n] = __builtin_amdgcn_mfma_f32_16x16x32_bf16(qf[1], kf1, s[n], 0, 0, 0);
    }
    // ---- scale + causal mask (only last tile can cross the diagonal) ----
    float vals[4][4];
    const bool diag = (t == nt - 1);
    #pragma unroll
    for (int n = 0; n < 4; n++)
      #pragma unroll
      for (int rg = 0; rg < 4; rg++) {
        float v = s[n][rg] * 0.125f;
        if (diag) {
          int kvp = kvb + n*16 + col16;
          int qp  = row0 + g*4 + rg;
          if (kvp > qp) v = -1e30f;
        }
        vals[n][rg] = v;
      }
    // ---- row max across the 16 lanes holding each row ----
    float rmax[4];
    #pragma unroll
    for (int rg = 0; rg < 4; rg++)
      rmax[rg] = fmaxf(fmaxf(vals[0][rg], vals[1][rg]), fmaxf(vals[2][rg], vals[3][rg]));
    #pragma unroll
    for (int off = 1; off < 16; off <<= 1)
      #pragma unroll
      for (int rg = 0; rg < 4; rg++)
        rmax[rg] = fmaxf(rmax[rg], __shfl_xor(rmax[rg], off));
    // ---- online softmax ----
    float scl[4], rsum[4];
    #pragma unroll
    for (int rg = 0; rg < 4; rg++) {
      float mn = fmaxf(m_r[rg], rmax[rg]);
      scl[rg] = __expf(m_r[rg] - mn);
      m_r[rg] = mn;
      rsum[rg] = 0.f;
    }
    #pragma unroll
    for (int n = 0; n < 4; n++)
      #pragma unroll
      for (int rg = 0; rg < 4; rg++) {
        float p = __expf(vals[n][rg] - m_r[rg]);
        vals[n][rg] = p;
        rsum[rg] += p;
      }
    #pragma unroll
    for (int off = 1; off < 16; off <<= 1)
      #pragma unroll
      for (int rg = 0; rg < 4; rg++)
        rsum[rg] += __shfl_xor(rsum[rg], off);
    #pragma unroll
    for (int rg = 0; rg < 4; rg++)
      l_r[rg] = l_r[rg] * scl[rg] + rsum[rg];
    #pragma unroll
    for (int n = 0; n < 4; n++)
      #pragma unroll
      for (int rg = 0; rg < 4; rg++)
        acc[n][rg] *= scl[rg];
    // ---- P -> per-wave LDS (XOR-swizzled), then back as A-fragments ----
    #pragma unroll
    for (int n = 0; n < 4; n++)
      #pragma unroll
      for (int rg = 0; rg < 4; rg++) {
        int row = g*4 + rg;
        int idx = (row * 64 + n*16 + col16) ^ ((row & 7) << 3);
        pl[idx] = (bf16)vals[n][rg];
      }
    bf16x8 pa[2];
    {
      int row = col16;
      int i0 = (row * 64 + 0  + g * 8) ^ ((row & 7) << 3);
      int i1 = (row * 64 + 32 + g * 8) ^ ((row & 7) << 3);
      pa[0] = *reinterpret_cast<const bf16x8*>(&pl[i0]);
      pa[1] = *reinterpret_cast<const bf16x8*>(&pl[i1]);
    }
    // ---- O += P V ----
    #pragma unroll
    for (int nd = 0; nd < 4; nd++) {
      const bf16* vrow = vt + ((size_t)(b * DH + nd*16 + col16)) * S_ + kvb + g * 8;
      bf16x8 v0 = *reinterpret_cast<const bf16x8*>(vrow);
      bf16x8 v1 = *reinterpret_cast<const bf16x8*>(vrow + 32);
      acc[nd] = __builtin_amdgcn_mfma_f32_16x16x32_bf16(pa[0], v0, acc[nd], 0, 0, 0);
      acc[nd] = __builtin_amdgcn_mfma_f32_16x16x32_bf16(pa[1], v1, acc[nd], 0, 0, 0);
    }
  }

  // ---- store partials to LDS ----
  #pragma unroll
  for (int n = 0; n < 4; n++)
    #pragma unroll
    for (int rg = 0; rg < 4; rg++)
      pacc[w][g*4 + rg][n*16 + col16] = acc[n][rg];
  if (col16 == 0) {
    #pragma unroll
    for (int rg = 0; rg < 4; rg++) {
      pm[w][g*4 + rg]  = m_r[rg];
      pl_[w][g*4 + rg] = l_r[rg];
    }
  }
  __syncthreads();

  // ---- combine 8 partials; 512 threads cover 16x64 outputs (2 each) ----
  const int tid = threadIdx.x;
  #pragma unroll
  for (int i = 0; i < 2; i++) {
    int idx = tid + i * 512;
    int row = idx >> 6, col = idx & 63;
    float M = -1e30f;
    #pragma unroll
    for (int ww = 0; ww < 8; ww++) M = fmaxf(M, pm[ww][row]);
    float L = 0.f, o = 0.f;
    #pragma unroll
    for (int ww = 0; ww < 8; ww++) {
      float e = __expf(pm[ww][row] - M);
      L += pl_[ww][row] * e;
      o += pacc[ww][row][col] * e;
    }
    out[((size_t)b * S_ + row0 + row) * DH + col] = o / L;
  }
}

extern "C" void kernel_launch(void* const* d_in, const int* in_sizes, int n_in,
                              void* d_out, int out_size, void* d_ws, size_t ws_size,
                              hipStream_t stream) {
  const float* q  = (const float*)d_in[0];
  const float* k  = (const float*)d_in[1];
  const float* v  = (const float*)d_in[2];
  const float* wq = (const float*)d_in[3];
  const float* wk = (const float*)d_in[4];
  const float* wv = (const float*)d_in[5];

  char* ws = (char*)d_ws;
  bf16* Wb = (bf16*)(ws);
  bf16* Qb = (bf16*)(ws + (512 << 10));
  bf16* Kb = (bf16*)(ws + (512 << 10) + (2 << 20));
  bf16* Vt = (bf16*)(ws + (512 << 10) + (4 << 20));

  wconv_kernel<<<dim3(DH * DIN / 256), 256, 0, stream>>>(wq, wk, wv, Wb);
  proj_kernel<<<dim3(B_ * S_ / 64, 3), 256, 0, stream>>>(q, k, v, Wb, Qb, Kb, Vt);
  attn_kernel<<<dim3(S_ / 16, B_), 512, 0, stream>>>(Qb, Kb, Vt, (float*)d_out);
}

// Round 4
// 118.873 us; speedup vs baseline: 1.5459x; 1.0691x over previous
//
#include <hip/hip_runtime.h>
#include <hip/hip_bf16.h>

#define B_  8
#define S_  2048
#define DIN 1024
#define DH  64

typedef __bf16 bf16;
typedef __attribute__((ext_vector_type(8))) __bf16 bf16x8;
typedef __attribute__((ext_vector_type(4))) float f32x4;

// ---------------- weight f32 -> bf16 ----------------
__global__ __launch_bounds__(256) void wconv_kernel(const float* __restrict__ wq,
                                                    const float* __restrict__ wk,
                                                    const float* __restrict__ wv,
                                                    bf16* __restrict__ wb) {
  int i = blockIdx.x * 256 + threadIdx.x;
  const int N = DH * DIN;
  wb[i]       = (bf16)wq[i];
  wb[N + i]   = (bf16)wk[i];
  wb[2*N + i] = (bf16)wv[i];
}

// ---------------- fused QKV projection, column-split across 4 waves ----------------
// grid: (M/16 = 1024, 3), block 256 (4 waves).
// Block stages its 16-row A tile (f32 -> bf16) in XOR-swizzled LDS once;
// wave w computes output columns w*16 .. w*16+15 over the full K=1024.
// No cross-wave reduction anywhere.
__global__ __launch_bounds__(256) void proj_kernel(
    const float* __restrict__ inq, const float* __restrict__ ink, const float* __restrict__ inv,
    const bf16* __restrict__ wb_all,
    bf16* __restrict__ qb, bf16* __restrict__ kb, bf16* __restrict__ vt) {
  const int p = blockIdx.y;
  const float* in = (p == 0) ? inq : ((p == 1) ? ink : inv);
  const bf16* wb = wb_all + (size_t)p * DH * DIN;
  const int tid  = threadIdx.x;
  const int lane = tid & 63;
  const int w    = tid >> 6;
  const int col16 = lane & 15, g = lane >> 4;
  const int row0 = blockIdx.x * 16;

  __shared__ bf16 albuf[16 * 1024];      // 32 KB, XOR-swizzled rows
  char* alb = (char*)albuf;

  // ---- stage A tile [16][1024] f32 -> bf16 LDS (swizzle byte ^= (row&7)<<4) ----
  #pragma unroll
  for (int c = 0; c < 8; c++) {
    int idx = c * 256 + tid;             // 2048 chunks of 8 bf16
    int row = idx >> 7;                  // 128 chunks per row
    int kk  = (idx & 127) * 8;
    const float4* ap = reinterpret_cast<const float4*>(in + (size_t)(row0 + row) * DIN + kk);
    float4 a0 = ap[0], a1 = ap[1];
    bf16x8 av;
    av[0]=(bf16)a0.x; av[1]=(bf16)a0.y; av[2]=(bf16)a0.z; av[3]=(bf16)a0.w;
    av[4]=(bf16)a1.x; av[5]=(bf16)a1.y; av[6]=(bf16)a1.z; av[7]=(bf16)a1.w;
    int byte = (row * 2048 + kk * 2) ^ ((row & 7) << 4);
    *reinterpret_cast<bf16x8*>(alb + byte) = av;
  }
  __syncthreads();

  // ---- wave w: 16x16 output tile, cols w*16..w*16+15, full K ----
  const int wcol = w * 16 + col16;
  const bf16* brow = wb + (size_t)wcol * DIN + g * 8;
  f32x4 acc = {};
  #pragma unroll 8
  for (int k0 = 0; k0 < DIN; k0 += 32) {
    int abyte = (col16 * 2048 + (k0 + g * 8) * 2) ^ ((col16 & 7) << 4);
    bf16x8 av = *reinterpret_cast<const bf16x8*>(alb + abyte);
    bf16x8 bv = *reinterpret_cast<const bf16x8*>(brow + k0);
    acc = __builtin_amdgcn_mfma_f32_16x16x32_bf16(av, bv, acc, 0, 0, 0);
  }

  // ---- store: C row = g*4+rg, col = wcol (same layout as proven round-2 store) ----
  #pragma unroll
  for (int rg = 0; rg < 4; rg++) {
    int rr = row0 + g*4 + rg;
    if (p == 0)      qb[(size_t)rr * DH + wcol] = (bf16)acc[rg];
    else if (p == 1) kb[(size_t)rr * DH + wcol] = (bf16)acc[rg];
    else {
      int bb = rr >> 11, ss = rr & 2047;
      vt[((size_t)bb * DH + wcol) * S_ + ss] = (bf16)acc[rg];
    }
  }
}

// ---------------- causal flash attention, KV-split across 8 waves ----------------
// grid: (S/16, B), block = 512 threads (8 waves).
__global__ __launch_bounds__(512) void attn_kernel(
    const bf16* __restrict__ qb, const bf16* __restrict__ kb, const bf16* __restrict__ vt,
    float* __restrict__ out) {
  const int qt = blockIdx.x;
  const int b  = blockIdx.y;
  const int lane = threadIdx.x & 63;
  const int w    = threadIdx.x >> 6;       // wave 0..7
  const int col16 = lane & 15, g = lane >> 4;
  const int row0 = qt * 16;                // q rows row0..row0+15

  __shared__ float pacc[8][16][64];
  __shared__ float pm[8][16];
  __shared__ float pl_[8][16];
  __shared__ bf16 plds[8][16 * 64];
  bf16* pl = plds[w];

  bf16x8 qf[2];
  {
    const bf16* qrow = qb + ((size_t)(b * S_ + row0 + col16)) * DH + g * 8;
    qf[0] = *reinterpret_cast<const bf16x8*>(qrow);
    qf[1] = *reinterpret_cast<const bf16x8*>(qrow + 32);
  }

  f32x4 acc[4] = {};
  float m_r[4], l_r[4];
  #pragma unroll
  for (int i = 0; i < 4; i++) { m_r[i] = -1e30f; l_r[i] = 0.f; }

  const int nt = (qt + 4) >> 2;            // causal kv-tile count (KVBLK=64)

  for (int t = w; t < nt; t += 8) {
    const int kvb = t * 64;
    f32x4 s[4] = {};
    #pragma unroll
    for (int n = 0; n < 4; n++) {
      const bf16* krow = kb + ((size_t)(b * S_ + kvb + n*16 + col16)) * DH + g * 8;
      bf16x8 kf0 = *reinterpret_cast<const bf16x8*>(krow);
      bf16x8 kf1 = *reinterpret_cast<const bf16x8*>(krow + 32);
      s[n] = __builtin_amdgcn_mfma_f32_16x16x32_bf16(qf[0], kf0, s[n], 0, 0, 0);
      s[n] = __builtin_amdgcn_mfma_f32_16x16x32_bf16(qf[1], kf1, s[n], 0, 0, 0);
    }
    float vals[4][4];
    const bool diag = (t == nt - 1);
    #pragma unroll
    for (int n = 0; n < 4; n++)
      #pragma unroll
      for (int rg = 0; rg < 4; rg++) {
        float v = s[n][rg] * 0.125f;
        if (diag) {
          int kvp = kvb + n*16 + col16;
          int qp  = row0 + g*4 + rg;
          if (kvp > qp) v = -1e30f;
        }
        vals[n][rg] = v;
      }
    float rmax[4];
    #pragma unroll
    for (int rg = 0; rg < 4; rg++)
      rmax[rg] = fmaxf(fmaxf(vals[0][rg], vals[1][rg]), fmaxf(vals[2][rg], vals[3][rg]));
    #pragma unroll
    for (int off = 1; off < 16; off <<= 1)
      #pragma unroll
      for (int rg = 0; rg < 4; rg++)
        rmax[rg] = fmaxf(rmax[rg], __shfl_xor(rmax[rg], off));
    float scl[4], rsum[4];
    #pragma unroll
    for (int rg = 0; rg < 4; rg++) {
      float mn = fmaxf(m_r[rg], rmax[rg]);
      scl[rg] = __expf(m_r[rg] - mn);
      m_r[rg] = mn;
      rsum[rg] = 0.f;
    }
    #pragma unroll
    for (int n = 0; n < 4; n++)
      #pragma unroll
      for (int rg = 0; rg < 4; rg++) {
        float pp = __expf(vals[n][rg] - m_r[rg]);
        vals[n][rg] = pp;
        rsum[rg] += pp;
      }
    #pragma unroll
    for (int off = 1; off < 16; off <<= 1)
      #pragma unroll
      for (int rg = 0; rg < 4; rg++)
        rsum[rg] += __shfl_xor(rsum[rg], off);
    #pragma unroll
    for (int rg = 0; rg < 4; rg++)
      l_r[rg] = l_r[rg] * scl[rg] + rsum[rg];
    #pragma unroll
    for (int n = 0; n < 4; n++)
      #pragma unroll
      for (int rg = 0; rg < 4; rg++)
        acc[n][rg] *= scl[rg];
    #pragma unroll
    for (int n = 0; n < 4; n++)
      #pragma unroll
      for (int rg = 0; rg < 4; rg++) {
        int row = g*4 + rg;
        int idx = (row * 64 + n*16 + col16) ^ ((row & 7) << 3);
        pl[idx] = (bf16)vals[n][rg];
      }
    bf16x8 pa[2];
    {
      int row = col16;
      int i0 = (row * 64 + 0  + g * 8) ^ ((row & 7) << 3);
      int i1 = (row * 64 + 32 + g * 8) ^ ((row & 7) << 3);
      pa[0] = *reinterpret_cast<const bf16x8*>(&pl[i0]);
      pa[1] = *reinterpret_cast<const bf16x8*>(&pl[i1]);
    }
    #pragma unroll
    for (int nd = 0; nd < 4; nd++) {
      const bf16* vrow = vt + ((size_t)(b * DH + nd*16 + col16)) * S_ + kvb + g * 8;
      bf16x8 v0 = *reinterpret_cast<const bf16x8*>(vrow);
      bf16x8 v1 = *reinterpret_cast<const bf16x8*>(vrow + 32);
      acc[nd] = __builtin_amdgcn_mfma_f32_16x16x32_bf16(pa[0], v0, acc[nd], 0, 0, 0);
      acc[nd] = __builtin_amdgcn_mfma_f32_16x16x32_bf16(pa[1], v1, acc[nd], 0, 0, 0);
    }
  }

  #pragma unroll
  for (int n = 0; n < 4; n++)
    #pragma unroll
    for (int rg = 0; rg < 4; rg++)
      pacc[w][g*4 + rg][n*16 + col16] = acc[n][rg];
  if (col16 == 0) {
    #pragma unroll
    for (int rg = 0; rg < 4; rg++) {
      pm[w][g*4 + rg]  = m_r[rg];
      pl_[w][g*4 + rg] = l_r[rg];
    }
  }
  __syncthreads();

  const int tid = threadIdx.x;
  #pragma unroll
  for (int i = 0; i < 2; i++) {
    int idx = tid + i * 512;
    int row = idx >> 6, col = idx & 63;
    float M = -1e30f;
    #pragma unroll
    for (int ww = 0; ww < 8; ww++) M = fmaxf(M, pm[ww][row]);
    float L = 0.f, o = 0.f;
    #pragma unroll
    for (int ww = 0; ww < 8; ww++) {
      float e = __expf(pm[ww][row] - M);
      L += pl_[ww][row] * e;
      o += pacc[ww][row][col] * e;
    }
    out[((size_t)b * S_ + row0 + row) * DH + col] = o / L;
  }
}

extern "C" void kernel_launch(void* const* d_in, const int* in_sizes, int n_in,
                              void* d_out, int out_size, void* d_ws, size_t ws_size,
                              hipStream_t stream) {
  const float* q  = (const float*)d_in[0];
  const float* k  = (const float*)d_in[1];
  const float* v  = (const float*)d_in[2];
  const float* wq = (const float*)d_in[3];
  const float* wk = (const float*)d_in[4];
  const float* wv = (const float*)d_in[5];

  char* ws = (char*)d_ws;
  bf16* Wb = (bf16*)(ws);
  bf16* Qb = (bf16*)(ws + (512 << 10));
  bf16* Kb = (bf16*)(ws + (512 << 10) + (2 << 20));
  bf16* Vt = (bf16*)(ws + (512 << 10) + (4 << 20));

  wconv_kernel<<<dim3(DH * DIN / 256), 256, 0, stream>>>(wq, wk, wv, Wb);
  proj_kernel<<<dim3(B_ * S_ / 16, 3), 256, 0, stream>>>(q, k, v, Wb, Qb, Kb, Vt);
  attn_kernel<<<dim3(S_ / 16, B_), 512, 0, stream>>>(Qb, Kb, Vt, (float*)d_out);
}

// Round 5
// 95.969 us; speedup vs baseline: 1.9149x; 1.2387x over previous
//
#include <hip/hip_runtime.h>
#include <hip/hip_bf16.h>

#define B_  8
#define S_  2048
#define DIN 1024
#define DH  64

typedef __bf16 bf16;
typedef __attribute__((ext_vector_type(8))) __bf16 bf16x8;
typedef __attribute__((ext_vector_type(4))) float f32x4;

// ---------------- weight f32 -> bf16, fragment-contiguous layout ----------------
// W'[p][w][kc][L][i] = W_p[w*16 + L%16][kc*32 + (L/16)*8 + i]
// so a wave's B-fragment load for (wave w, k0=kc*32) is 64 lanes x 16B contiguous.
__global__ __launch_bounds__(256) void wconv_kernel(const float* __restrict__ wq,
                                                    const float* __restrict__ wk,
                                                    const float* __restrict__ wv,
                                                    bf16* __restrict__ wb) {
  int i = blockIdx.x * 256 + threadIdx.x;    // 24576 threads total
  int L  = i & 63;
  int kc = (i >> 6) & 31;
  int w  = (i >> 11) & 3;
  int p  = i >> 13;
  const float* src = (p == 0) ? wq : ((p == 1) ? wk : wv);
  int row = w * 16 + (L & 15);
  int k8  = kc * 32 + (L >> 4) * 8;
  const float4* ap = reinterpret_cast<const float4*>(src + (size_t)row * DIN + k8);
  float4 a0 = ap[0], a1 = ap[1];
  bf16x8 av;
  av[0]=(bf16)a0.x; av[1]=(bf16)a0.y; av[2]=(bf16)a0.z; av[3]=(bf16)a0.w;
  av[4]=(bf16)a1.x; av[5]=(bf16)a1.y; av[6]=(bf16)a1.z; av[7]=(bf16)a1.w;
  *reinterpret_cast<bf16x8*>(wb + ((size_t)((p*4 + w)*32 + kc)*64 + L) * 8) = av;
}

// ---------------- fused QKV projection, column-split across 4 waves ----------------
// grid: (M/16 = 1024, 3), block 256 (4 waves).
// Stage A tile [16][1024] f32->bf16 into XOR-swizzled LDS with a 16-deep
// register load batch (MLP), then wave w computes output cols w*16..w*16+15.
__global__ __launch_bounds__(256) void proj_kernel(
    const float* __restrict__ inq, const float* __restrict__ ink, const float* __restrict__ inv,
    const bf16* __restrict__ wb_all,
    bf16* __restrict__ qb, bf16* __restrict__ kb, bf16* __restrict__ vt) {
  const int p = blockIdx.y;
  const float* in = (p == 0) ? inq : ((p == 1) ? ink : inv);
  const int tid  = threadIdx.x;
  const int lane = tid & 63;
  const int w    = tid >> 6;
  const int col16 = lane & 15, g = lane >> 4;
  const int row0 = blockIdx.x * 16;

  __shared__ bf16 albuf[16 * 1024];      // 32 KB, XOR-swizzled rows
  char* alb = (char*)albuf;

  // ---- stage: issue all 16 loads first, then cvt+write ----
  float4 st[16];
  const float* abase = in + (size_t)row0 * DIN;
  #pragma unroll
  for (int c = 0; c < 8; c++) {
    int idx = c * 256 + tid;             // 2048 chunks of 8 floats
    int row = idx >> 7;
    int kk  = (idx & 127) * 8;
    const float4* ap = reinterpret_cast<const float4*>(abase + (size_t)row * DIN + kk);
    st[2*c]   = ap[0];
    st[2*c+1] = ap[1];
  }
  #pragma unroll
  for (int c = 0; c < 8; c++) {
    int idx = c * 256 + tid;
    int row = idx >> 7;
    int kk  = (idx & 127) * 8;
    float4 a0 = st[2*c], a1 = st[2*c+1];
    bf16x8 av;
    av[0]=(bf16)a0.x; av[1]=(bf16)a0.y; av[2]=(bf16)a0.z; av[3]=(bf16)a0.w;
    av[4]=(bf16)a1.x; av[5]=(bf16)a1.y; av[6]=(bf16)a1.z; av[7]=(bf16)a1.w;
    int byte = (row * 2048 + kk * 2) ^ ((row & 7) << 4);
    *reinterpret_cast<bf16x8*>(alb + byte) = av;
  }
  __syncthreads();

  // ---- wave w: 16x16 output tile, cols w*16..w*16+15, full K ----
  const int wcol = w * 16 + col16;
  const bf16* bbase = wb_all + (size_t)(p*4 + w) * (32 * 64 * 8) + lane * 8;
  f32x4 acc = {};
  #pragma unroll 8
  for (int k0 = 0; k0 < DIN; k0 += 32) {
    int abyte = (col16 * 2048 + (k0 + g * 8) * 2) ^ ((col16 & 7) << 4);
    bf16x8 av = *reinterpret_cast<const bf16x8*>(alb + abyte);
    bf16x8 bv = *reinterpret_cast<const bf16x8*>(bbase + (k0 >> 5) * 512);
    acc = __builtin_amdgcn_mfma_f32_16x16x32_bf16(av, bv, acc, 0, 0, 0);
  }

  // ---- store: C row = g*4+rg, col = wcol ----
  #pragma unroll
  for (int rg = 0; rg < 4; rg++) {
    int rr = row0 + g*4 + rg;
    if (p == 0)      qb[(size_t)rr * DH + wcol] = (bf16)acc[rg];
    else if (p == 1) kb[(size_t)rr * DH + wcol] = (bf16)acc[rg];
    else {
      int bb = rr >> 11, ss = rr & 2047;
      vt[((size_t)bb * DH + wcol) * S_ + ss] = (bf16)acc[rg];
    }
  }
}

// ---------------- causal flash attention, KV-split across 8 waves ----------------
// grid: (S/16, B), block = 512 threads (8 waves).  (unchanged, proven)
__global__ __launch_bounds__(512) void attn_kernel(
    const bf16* __restrict__ qb, const bf16* __restrict__ kb, const bf16* __restrict__ vt,
    float* __restrict__ out) {
  const int qt = blockIdx.x;
  const int b  = blockIdx.y;
  const int lane = threadIdx.x & 63;
  const int w    = threadIdx.x >> 6;       // wave 0..7
  const int col16 = lane & 15, g = lane >> 4;
  const int row0 = qt * 16;                // q rows row0..row0+15

  __shared__ float pacc[8][16][64];
  __shared__ float pm[8][16];
  __shared__ float pl_[8][16];
  __shared__ bf16 plds[8][16 * 64];
  bf16* pl = plds[w];

  bf16x8 qf[2];
  {
    const bf16* qrow = qb + ((size_t)(b * S_ + row0 + col16)) * DH + g * 8;
    qf[0] = *reinterpret_cast<const bf16x8*>(qrow);
    qf[1] = *reinterpret_cast<const bf16x8*>(qrow + 32);
  }

  f32x4 acc[4] = {};
  float m_r[4], l_r[4];
  #pragma unroll
  for (int i = 0; i < 4; i++) { m_r[i] = -1e30f; l_r[i] = 0.f; }

  const int nt = (qt + 4) >> 2;            // causal kv-tile count (KVBLK=64)

  for (int t = w; t < nt; t += 8) {
    const int kvb = t * 64;
    f32x4 s[4] = {};
    #pragma unroll
    for (int n = 0; n < 4; n++) {
      const bf16* krow = kb + ((size_t)(b * S_ + kvb + n*16 + col16)) * DH + g * 8;
      bf16x8 kf0 = *reinterpret_cast<const bf16x8*>(krow);
      bf16x8 kf1 = *reinterpret_cast<const bf16x8*>(krow + 32);
      s[n] = __builtin_amdgcn_mfma_f32_16x16x32_bf16(qf[0], kf0, s[n], 0, 0, 0);
      s[n] = __builtin_amdgcn_mfma_f32_16x16x32_bf16(qf[1], kf1, s[n], 0, 0, 0);
    }
    float vals[4][4];
    const bool diag = (t == nt - 1);
    #pragma unroll
    for (int n = 0; n < 4; n++)
      #pragma unroll
      for (int rg = 0; rg < 4; rg++) {
        float v = s[n][rg] * 0.125f;
        if (diag) {
          int kvp = kvb + n*16 + col16;
          int qp  = row0 + g*4 + rg;
          if (kvp > qp) v = -1e30f;
        }
        vals[n][rg] = v;
      }
    float rmax[4];
    #pragma unroll
    for (int rg = 0; rg < 4; rg++)
      rmax[rg] = fmaxf(fmaxf(vals[0][rg], vals[1][rg]), fmaxf(vals[2][rg], vals[3][rg]));
    #pragma unroll
    for (int off = 1; off < 16; off <<= 1)
      #pragma unroll
      for (int rg = 0; rg < 4; rg++)
        rmax[rg] = fmaxf(rmax[rg], __shfl_xor(rmax[rg], off));
    float scl[4], rsum[4];
    #pragma unroll
    for (int rg = 0; rg < 4; rg++) {
      float mn = fmaxf(m_r[rg], rmax[rg]);
      scl[rg] = __expf(m_r[rg] - mn);
      m_r[rg] = mn;
      rsum[rg] = 0.f;
    }
    #pragma unroll
    for (int n = 0; n < 4; n++)
      #pragma unroll
      for (int rg = 0; rg < 4; rg++) {
        float pp = __expf(vals[n][rg] - m_r[rg]);
        vals[n][rg] = pp;
        rsum[rg] += pp;
      }
    #pragma unroll
    for (int off = 1; off < 16; off <<= 1)
      #pragma unroll
      for (int rg = 0; rg < 4; rg++)
        rsum[rg] += __shfl_xor(rsum[rg], off);
    #pragma unroll
    for (int rg = 0; rg < 4; rg++)
      l_r[rg] = l_r[rg] * scl[rg] + rsum[rg];
    #pragma unroll
    for (int n = 0; n < 4; n++)
      #pragma unroll
      for (int rg = 0; rg < 4; rg++)
        acc[n][rg] *= scl[rg];
    #pragma unroll
    for (int n = 0; n < 4; n++)
      #pragma unroll
      for (int rg = 0; rg < 4; rg++) {
        int row = g*4 + rg;
        int idx = (row * 64 + n*16 + col16) ^ ((row & 7) << 3);
        pl[idx] = (bf16)vals[n][rg];
      }
    bf16x8 pa[2];
    {
      int row = col16;
      int i0 = (row * 64 + 0  + g * 8) ^ ((row & 7) << 3);
      int i1 = (row * 64 + 32 + g * 8) ^ ((row & 7) << 3);
      pa[0] = *reinterpret_cast<const bf16x8*>(&pl[i0]);
      pa[1] = *reinterpret_cast<const bf16x8*>(&pl[i1]);
    }
    #pragma unroll
    for (int nd = 0; nd < 4; nd++) {
      const bf16* vrow = vt + ((size_t)(b * DH + nd*16 + col16)) * S_ + kvb + g * 8;
      bf16x8 v0 = *reinterpret_cast<const bf16x8*>(vrow);
      bf16x8 v1 = *reinterpret_cast<const bf16x8*>(vrow + 32);
      acc[nd] = __builtin_amdgcn_mfma_f32_16x16x32_bf16(pa[0], v0, acc[nd], 0, 0, 0);
      acc[nd] = __builtin_amdgcn_mfma_f32_16x16x32_bf16(pa[1], v1, acc[nd], 0, 0, 0);
    }
  }

  #pragma unroll
  for (int n = 0; n < 4; n++)
    #pragma unroll
    for (int rg = 0; rg < 4; rg++)
      pacc[w][g*4 + rg][n*16 + col16] = acc[n][rg];
  if (col16 == 0) {
    #pragma unroll
    for (int rg = 0; rg < 4; rg++) {
      pm[w][g*4 + rg]  = m_r[rg];
      pl_[w][g*4 + rg] = l_r[rg];
    }
  }
  __syncthreads();

  const int tid = threadIdx.x;
  #pragma unroll
  for (int i = 0; i < 2; i++) {
    int idx = tid + i * 512;
    int row = idx >> 6, col = idx & 63;
    float M = -1e30f;
    #pragma unroll
    for (int ww = 0; ww < 8; ww++) M = fmaxf(M, pm[ww][row]);
    float L = 0.f, o = 0.f;
    #pragma unroll
    for (int ww = 0; ww < 8; ww++) {
      float e = __expf(pm[ww][row] - M);
      L += pl_[ww][row] * e;
      o += pacc[ww][row][col] * e;
    }
    out[((size_t)b * S_ + row0 + row) * DH + col] = o / L;
  }
}

extern "C" void kernel_launch(void* const* d_in, const int* in_sizes, int n_in,
                              void* d_out, int out_size, void* d_ws, size_t ws_size,
                              hipStream_t stream) {
  const float* q  = (const float*)d_in[0];
  const float* k  = (const float*)d_in[1];
  const float* v  = (const float*)d_in[2];
  const float* wq = (const float*)d_in[3];
  const float* wk = (const float*)d_in[4];
  const float* wv = (const float*)d_in[5];

  char* ws = (char*)d_ws;
  bf16* Wb = (bf16*)(ws);                         // 1.5 MB fragment-ordered weights
  bf16* Qb = (bf16*)(ws + 1572864);               // 2 MB
  bf16* Kb = (bf16*)(ws + 1572864 + 2097152);     // 2 MB
  bf16* Vt = (bf16*)(ws + 1572864 + 4194304);     // 2 MB (transposed [B][DH][S])

  wconv_kernel<<<dim3(96), 256, 0, stream>>>(wq, wk, wv, Wb);
  proj_kernel<<<dim3(B_ * S_ / 16, 3), 256, 0, stream>>>(q, k, v, Wb, Qb, Kb, Vt);
  attn_kernel<<<dim3(S_ / 16, B_), 512, 0, stream>>>(Qb, Kb, Vt, (float*)d_out);
}